// Round 9
// baseline (415.563 us; speedup 1.0000x reference)
//
#include <hip/hip_runtime.h>

#define N_NODES 50000
#define N_EDGES 800000
#define IN_C 8
#define OUT_C 16
#define EDGE_F 8
#define HEADS 4
#define HID 64
#define GDIM (HEADS*HID)   // 256
#define FINAL 128
#define NEG_SLOPE 0.2f
#define EB ((N_EDGES+255)/256)      // 3125
#define NBLK 196                    // ceil(N_NODES/256)

__device__ __forceinline__ int clampn(int v) {
    return v < 0 ? 0 : (v >= N_NODES ? N_NODES - 1 : v);
}
__device__ __forceinline__ unsigned short f32_to_bf16(float f) {
    unsigned u = __float_as_uint(f);
    unsigned r = (u + 0x7fffu + ((u >> 16) & 1u)) >> 16;   // RNE
    return (unsigned short)r;
}
__device__ __forceinline__ float bf16lo(unsigned u) { return __uint_as_float(u << 16); }
__device__ __forceinline__ float bf16hi(unsigned u) { return __uint_as_float(u & 0xffff0000u); }

// ---------- CSR build ----------
__global__ __launch_bounds__(256) void k_hist(const int* __restrict__ dst,
                                              int* __restrict__ cnt,
                                              int* __restrict__ rnk)
{
    int e = blockIdx.x * 256 + threadIdx.x;
    if (e >= N_EDGES) return;
    rnk[e] = atomicAdd(&cnt[clampn(dst[e])], 1);
}

__global__ __launch_bounds__(256) void k_part(const int* __restrict__ cnt,
                                              int* __restrict__ part)
{
    int i = blockIdx.x * 256 + threadIdx.x;
    int v = (i < N_NODES) ? cnt[i] : 0;
#pragma unroll
    for (int off = 32; off; off >>= 1) v += __shfl_down(v, off);
    __shared__ int ws[4];
    if ((threadIdx.x & 63) == 0) ws[threadIdx.x >> 6] = v;
    __syncthreads();
    if (threadIdx.x == 0) part[blockIdx.x] = ws[0] + ws[1] + ws[2] + ws[3];
}

__global__ __launch_bounds__(256) void k_scan1(const int* __restrict__ part,
                                               int* __restrict__ partscan)
{
    int t = threadIdx.x;
    int v = (t < NBLK) ? part[t] : 0;
    int lane = t & 63, wid = t >> 6;
    int incl = v;
#pragma unroll
    for (int off = 1; off < 64; off <<= 1) {
        int u = __shfl_up(incl, off);
        if (lane >= off) incl += u;
    }
    __shared__ int wsum[4];
    if (lane == 63) wsum[wid] = incl;
    __syncthreads();
    int add = 0;
    for (int w = 0; w < wid; w++) add += wsum[w];
    partscan[t] = incl - v + add;   // exclusive
}

__global__ __launch_bounds__(256) void k_add(const int* __restrict__ cnt,
                                             const int* __restrict__ partscan,
                                             int* __restrict__ offs)
{
    int i = blockIdx.x * 256 + threadIdx.x;
    int v = (i < N_NODES) ? cnt[i] : 0;
    int lane = threadIdx.x & 63, wid = threadIdx.x >> 6;
    int incl = v;
#pragma unroll
    for (int off = 1; off < 64; off <<= 1) {
        int u = __shfl_up(incl, off);
        if (lane >= off) incl += u;
    }
    __shared__ int wsum[4];
    if (lane == 63) wsum[wid] = incl;
    __syncthreads();
    int add = partscan[blockIdx.x];
    for (int w = 0; w < wid; w++) add += wsum[w];
    if (i < N_NODES) offs[i] = incl - v + add;
    if (i == 0) offs[N_NODES] = N_EDGES;
}

// ---------- K_scatter: (src, edge-id) pairs into dst-CSR order ----------
__global__ __launch_bounds__(256) void k_scatter(
    const int* __restrict__ src, const int* __restrict__ dst,
    const int* __restrict__ rnk, const int* __restrict__ offs,
    int2* __restrict__ se_csr)
{
    int e = blockIdx.x * 256 + threadIdx.x;
    if (e >= N_EDGES) return;
    int p = offs[clampn(dst[e])] + rnk[e];
    se_csr[p] = make_int2(clampn(src[e]), e);
}

// ---------- K_fold: w_src[c,h] = sum_k lin[c,h*64+k]*att_src[h,k]  (and dst) ----------
__global__ __launch_bounds__(64) void k_fold(
    const float* __restrict__ gat_lin,
    const float* __restrict__ att_src_w, const float* __restrict__ att_dst_w,
    float* __restrict__ wsrc, float* __restrict__ wdst)
{
    int t = threadIdx.x;           // t = c*4 + h
    int c = t >> 2, h = t & 3;
    float ws = 0.f, wd = 0.f;
    for (int k = 0; k < HID; k++) {
        float l = gat_lin[c * GDIM + h * HID + k];
        ws += l * att_src_w[h * HID + k];
        wd += l * att_dst_w[h * HID + k];
    }
    wsrc[t] = ws;
    wdst[t] = wd;
}

// ---------- K2T: block-per-node T-factorized NNConv + h + folded logits ----------
// T[d,f,i] = sum_{e->d} ea[e,f]*x[s_e,i]; 4 waves split the edge list, LDS-reduce.
__global__ __launch_bounds__(256) void k2T_blk(
    const float* __restrict__ x,
    const int2* __restrict__ se_csr, const int* __restrict__ offs,
    const float* __restrict__ ea,
    const float* __restrict__ mlp_w, const float* __restrict__ mlp_b,
    const float* __restrict__ ecc_root, const float* __restrict__ ecc_bias,
    const float* __restrict__ wsrc, const float* __restrict__ wdst,
    float* __restrict__ h_tab, float* __restrict__ asrc, float* __restrict__ adst)
{
    __shared__ float smW[EDGE_F * IN_C * OUT_C];   // 1024: [f*8+i][o]
    __shared__ float smb[IN_C * OUT_C];            // 128
    __shared__ float sws[64], swd[64];
    __shared__ float sT[4][64];
    __shared__ float sxs[4][8];
    __shared__ float sh[16];
    for (int i = threadIdx.x; i < EDGE_F * IN_C * OUT_C; i += 256) smW[i] = mlp_w[i];
    if (threadIdx.x < 128) smb[threadIdx.x] = mlp_b[threadIdx.x];
    else if (threadIdx.x < 192) sws[threadIdx.x - 128] = wsrc[threadIdx.x - 128];
    else swd[threadIdx.x - 192] = wdst[threadIdx.x - 192];

    int w = threadIdx.x >> 6, lane = threadIdx.x & 63;
    int n = blockIdx.x;
    int f = lane >> 3, i = lane & 7;
    int beg = offs[n], end = offs[n + 1];

    float t0 = 0.f, t1 = 0.f, xs = 0.f;
    int j = beg + w;
    for (; j + 4 < end; j += 8) {          // unroll 2, wave-stride 4
        int2 se0 = se_csr[j], se1 = se_csr[j + 4];
        float a0 = ea[(size_t)se0.y * EDGE_F + f];
        float a1 = ea[(size_t)se1.y * EDGE_F + f];
        float x0 = x[se0.x * IN_C + i];
        float x1 = x[se1.x * IN_C + i];
        t0 += a0 * x0; t1 += a1 * x1;
        xs += x0 + x1;
    }
    for (; j < end; j += 4) {
        int2 se = se_csr[j];
        float a = ea[(size_t)se.y * EDGE_F + f];
        float xv = x[se.x * IN_C + i];
        t0 += a * xv;
        xs += xv;
    }
    sT[w][lane] = t0 + t1;
    if (f == 0) sxs[w][i] = xs;
    __syncthreads();
    if (w != 0) return;

    float tf = sT[0][lane] + sT[1][lane] + sT[2][lane] + sT[3][lane];
    sT[0][lane] = tf;
    if (f == 0) sxs[0][i] = sxs[0][i] + sxs[1][i] + sxs[2][i] + sxs[3][i];

    int o = lane;
    if (lane < 16) {
        float v = ecc_bias[o];
#pragma unroll 8
        for (int jj = 0; jj < 64; jj++)
            v += smW[jj * OUT_C + o] * sT[0][jj];
#pragma unroll
        for (int ii = 0; ii < IN_C; ii++) {
            v += smb[ii * OUT_C + o] * sxs[0][ii];
            v += x[n * IN_C + ii] * ecc_root[ii * OUT_C + o];
        }
        float hv = fmaxf(v, 0.f);
        sh[o] = hv;
        h_tab[n * OUT_C + o] = hv;
    }
    if (lane < 4) {
        float as = 0.f, ad = 0.f;
#pragma unroll
        for (int c = 0; c < 16; c++) {
            as += sh[c] * sws[c * 4 + lane];
            ad += sh[c] * swd[c * 4 + lane];
        }
        asrc[n * HEADS + lane] = as;
        adst[n * HEADS + lane] = ad;
    }
}

// ---------- K_gatU: U-factorized GAT. 2 nodes/block, 2 waves/node. ----------
// U[d,h,c] = sum_e exp(leaky(asrc[s]+adst[d]))_h * h[s,c];
// out[d, h*64+k] = (sum_c U[h,c]*lin[c,h*64+k]) / den[h]
__global__ __launch_bounds__(256) void k_gatU(
    const int* __restrict__ offs, const int2* __restrict__ se_csr,
    const float* __restrict__ asrc, const float* __restrict__ adst,
    const float* __restrict__ h_tab, const float* __restrict__ gat_lin,
    unsigned short* __restrict__ outg)
{
    __shared__ float slin[OUT_C * GDIM];   // 16 KB: [c][d]
    __shared__ float sU[4][64];
    __shared__ float sden[4][HEADS];
    for (int idx = threadIdx.x; idx < OUT_C * GDIM; idx += 256) slin[idx] = gat_lin[idx];

    int t = threadIdx.x;
    int w = t >> 6, lane = t & 63;
    int local = w >> 1, q = w & 1;
    int n = blockIdx.x * 2 + local;
    int h = lane >> 4, c = lane & 15;
    float adsth = adst[n * HEADS + h];
    int beg = offs[n], end = offs[n + 1];

    float U = 0.f, denp = 0.f;
    int j = beg + q;
    for (; j + 2 < end; j += 4) {          // unroll 2, wave-stride 2
        int2 se0 = se_csr[j], se1 = se_csr[j + 2];
        float av0 = asrc[se0.x * HEADS + h];
        float av1 = asrc[se1.x * HEADS + h];
        float h0 = h_tab[se0.x * OUT_C + c];
        float h1 = h_tab[se1.x * OUT_C + c];
        float v0 = av0 + adsth; v0 = v0 > 0.f ? v0 : NEG_SLOPE * v0;
        float v1 = av1 + adsth; v1 = v1 > 0.f ? v1 : NEG_SLOPE * v1;
        float p0 = __expf(v0), p1 = __expf(v1);
        denp += p0 + p1;
        U += p0 * h0 + p1 * h1;
    }
    for (; j < end; j += 2) {
        int2 se = se_csr[j];
        float av = asrc[se.x * HEADS + h];
        float hv = h_tab[se.x * OUT_C + c];
        float v = av + adsth; v = v > 0.f ? v : NEG_SLOPE * v;
        float p = __expf(v);
        denp += p;
        U += p * hv;
    }
    sU[w][lane] = U;
    if (c == 0) sden[w][h] = denp;
    __syncthreads();
    if (q != 0) return;

    // sum the node's two waves (w and w+1); epilogue by wave w
    float U2 = sU[w][lane] + sU[w + 1][lane];
    sU[w][lane] = U2;
    if (c == 0) sden[w][h] = sden[w][h] + sden[w + 1][h];

#pragma unroll
    for (int j2 = 0; j2 < 4; j2++) {
        float acc = 0.f;
#pragma unroll
        for (int cc = 0; cc < 16; cc++)
            acc += sU[w][j2 * 16 + cc] * slin[cc * GDIM + j2 * 64 + lane];
        float dv = sden[w][j2] + 1e-16f;
        outg[(size_t)n * GDIM + j2 * 64 + lane] = f32_to_bf16(acc / dv);
    }
}

// ---------- K6: y = relu(outg + gat_bias) @ fc_w + fc_b ----------
#define BM 64
#define BK6 16
__global__ __launch_bounds__(256) void k6_final(
    const unsigned short* __restrict__ outg, const float* __restrict__ gat_bias,
    const float* __restrict__ fc_w, const float* __restrict__ fc_b,
    float* __restrict__ y)
{
    __shared__ float sA[BK6][BM + 4];
    __shared__ float sW[BK6][FINAL];
    int tid = threadIdx.x;
    int r0 = blockIdx.x * BM;
    int tcol = (tid & 31) * 4;
    int trow = (tid >> 5) * 8;

    float acc[8][4];
#pragma unroll
    for (int r = 0; r < 8; r++)
#pragma unroll
        for (int c = 0; c < 4; c++) acc[r][c] = 0.f;

    int ar = tid >> 2;
    int ak = (tid & 3) * 4;

    for (int k0 = 0; k0 < GDIM; k0 += BK6) {
        int row = r0 + ar;
        float4 av = make_float4(0.f, 0.f, 0.f, 0.f);
        if (row < N_NODES) {
            uint2 raw = *(const uint2*)&outg[(size_t)row * GDIM + k0 + ak];
            av = make_float4(bf16lo(raw.x), bf16hi(raw.x), bf16lo(raw.y), bf16hi(raw.y));
        }
        float4 bv = *(const float4*)&gat_bias[k0 + ak];
        av.x = fmaxf(av.x + bv.x, 0.f);
        av.y = fmaxf(av.y + bv.y, 0.f);
        av.z = fmaxf(av.z + bv.z, 0.f);
        av.w = fmaxf(av.w + bv.w, 0.f);
        sA[ak + 0][ar] = av.x;
        sA[ak + 1][ar] = av.y;
        sA[ak + 2][ar] = av.z;
        sA[ak + 3][ar] = av.w;
#pragma unroll
        for (int p = 0; p < 2; p++) {
            int kk = (tid >> 5) + p * 8;
            int c = (tid & 31) * 4;
            *(float4*)&sW[kk][c] = *(const float4*)&fc_w[(size_t)(k0 + kk) * FINAL + c];
        }
        __syncthreads();
#pragma unroll
        for (int kk = 0; kk < BK6; kk++) {
            float4 w = *(const float4*)&sW[kk][tcol];
            float4 a0 = *(const float4*)&sA[kk][trow];
            float4 a1 = *(const float4*)&sA[kk][trow + 4];
            float a[8] = {a0.x, a0.y, a0.z, a0.w, a1.x, a1.y, a1.z, a1.w};
#pragma unroll
            for (int r = 0; r < 8; r++) {
                acc[r][0] += a[r] * w.x;
                acc[r][1] += a[r] * w.y;
                acc[r][2] += a[r] * w.z;
                acc[r][3] += a[r] * w.w;
            }
        }
        __syncthreads();
    }

    float4 fb = *(const float4*)&fc_b[tcol];
#pragma unroll
    for (int r = 0; r < 8; r++) {
        int row = r0 + trow + r;
        if (row < N_NODES) {
            *(float4*)&y[(size_t)row * FINAL + tcol] =
                make_float4(acc[r][0] + fb.x, acc[r][1] + fb.y,
                            acc[r][2] + fb.z, acc[r][3] + fb.w);
        }
    }
}

extern "C" void kernel_launch(void* const* d_in, const int* in_sizes, int n_in,
                              void* d_out, int out_size, void* d_ws, size_t ws_size,
                              hipStream_t stream)
{
    const float* x        = (const float*)d_in[0];
    const int*   ei       = (const int*)d_in[1];
    const float* ea       = (const float*)d_in[2];
    const float* ecc_root = (const float*)d_in[3];
    const float* ecc_bias = (const float*)d_in[4];
    const float* mlp_w    = (const float*)d_in[5];
    const float* mlp_b    = (const float*)d_in[6];
    const float* gat_lin  = (const float*)d_in[7];
    const float* att_src  = (const float*)d_in[8];
    const float* att_dst  = (const float*)d_in[9];
    const float* gat_bias = (const float*)d_in[10];
    const float* fc_w     = (const float*)d_in[11];
    const float* fc_b     = (const float*)d_in[12];
    float* y = (float*)d_out;

    const int* src = ei;
    const int* dst = ei + N_EDGES;

    // workspace layout
    float* h_tab = (float*)d_ws;                                         // N*16 f32 (3.2 MB)
    unsigned short* outg = (unsigned short*)(h_tab + (size_t)N_NODES * OUT_C); // N*256 bf16 (25.6 MB)
    float* asrc = (float*)(outg + (size_t)N_NODES * GDIM);               // N*4
    float* adst = asrc + (size_t)N_NODES * HEADS;                        // N*4
    float* wsrc = adst + (size_t)N_NODES * HEADS;                        // 64
    float* wdst = wsrc + 64;                                             // 64
    int*   cnt      = (int*)(wdst + 64);                                 // N
    int*   offs     = cnt + N_NODES;                                     // N+1
    int*   part     = offs + N_NODES + 1;                                // 256
    int*   partscan = part + 256;                                        // 256
    int*   rnk      = partscan + 256;                                    // E
    int2*  se_csr   = (int2*)(rnk + N_EDGES);                            // E int2 (6.4 MB)

    hipMemsetAsync(cnt, 0, sizeof(int) * N_NODES, stream);

    k_hist   <<<EB, 256, 0, stream>>>(dst, cnt, rnk);
    k_fold   <<<1, 64, 0, stream>>>(gat_lin, att_src, att_dst, wsrc, wdst);
    k_part   <<<NBLK, 256, 0, stream>>>(cnt, part);
    k_scan1  <<<1, 256, 0, stream>>>(part, partscan);
    k_add    <<<NBLK, 256, 0, stream>>>(cnt, partscan, offs);
    k_scatter<<<EB, 256, 0, stream>>>(src, dst, rnk, offs, se_csr);

    k2T_blk  <<<N_NODES, 256, 0, stream>>>(x, se_csr, offs, ea, mlp_w, mlp_b,
                                           ecc_root, ecc_bias, wsrc, wdst,
                                           h_tab, asrc, adst);
    k_gatU   <<<N_NODES / 2, 256, 0, stream>>>(offs, se_csr, asrc, adst,
                                               h_tab, gat_lin, outg);
    k6_final <<<(N_NODES + BM - 1) / BM, 256, 0, stream>>>(outg, gat_bias, fc_w, fc_b, y);
}

// Round 10
// 324.310 us; speedup vs baseline: 1.2814x; 1.2814x over previous
//
#include <hip/hip_runtime.h>

#define N_NODES 50000
#define N_EDGES 800000
#define IN_C 8
#define OUT_C 16
#define EDGE_F 8
#define HEADS 4
#define HID 64
#define GDIM (HEADS*HID)   // 256
#define FINAL 128
#define NEG_SLOPE 0.2f
#define EB ((N_EDGES+255)/256)      // 3125
#define NBLK 196                    // ceil(N_NODES/256)

__device__ __forceinline__ int clampn(int v) {
    return v < 0 ? 0 : (v >= N_NODES ? N_NODES - 1 : v);
}

// ---------- K_histfold: dst histogram + rank, plus folded attention weights ----------
__global__ __launch_bounds__(256) void k_histfold(
    const int* __restrict__ dst, int* __restrict__ cnt, int* __restrict__ rnk,
    const float* __restrict__ gat_lin,
    const float* __restrict__ att_src_w, const float* __restrict__ att_dst_w,
    float* __restrict__ wsrc, float* __restrict__ wdst)
{
    if (blockIdx.x < EB) {
        int e = blockIdx.x * 256 + threadIdx.x;
        if (e >= N_EDGES) return;
        rnk[e] = atomicAdd(&cnt[clampn(dst[e])], 1);
    } else {
        int t = threadIdx.x;           // t = c*4 + h
        if (t >= 64) return;
        int c = t >> 2, h = t & 3;
        float ws = 0.f, wd = 0.f;
        for (int k = 0; k < HID; k++) {
            float l = gat_lin[c * GDIM + h * HID + k];
            ws += l * att_src_w[h * HID + k];
            wd += l * att_dst_w[h * HID + k];
        }
        wsrc[t] = ws;
        wdst[t] = wd;
    }
}

// ---------- scan pipeline ----------
__global__ __launch_bounds__(256) void k_part(const int* __restrict__ cnt,
                                              int* __restrict__ part)
{
    int i = blockIdx.x * 256 + threadIdx.x;
    int v = (i < N_NODES) ? cnt[i] : 0;
#pragma unroll
    for (int off = 32; off; off >>= 1) v += __shfl_down(v, off);
    __shared__ int ws[4];
    if ((threadIdx.x & 63) == 0) ws[threadIdx.x >> 6] = v;
    __syncthreads();
    if (threadIdx.x == 0) part[blockIdx.x] = ws[0] + ws[1] + ws[2] + ws[3];
}

__global__ __launch_bounds__(256) void k_scan1(const int* __restrict__ part,
                                               int* __restrict__ partscan)
{
    int t = threadIdx.x;
    int v = (t < NBLK) ? part[t] : 0;
    int lane = t & 63, wid = t >> 6;
    int incl = v;
#pragma unroll
    for (int off = 1; off < 64; off <<= 1) {
        int u = __shfl_up(incl, off);
        if (lane >= off) incl += u;
    }
    __shared__ int wsum[4];
    if (lane == 63) wsum[wid] = incl;
    __syncthreads();
    int add = 0;
    for (int w = 0; w < wid; w++) add += wsum[w];
    partscan[t] = incl - v + add;   // exclusive
}

__global__ __launch_bounds__(256) void k_add(const int* __restrict__ cnt,
                                             const int* __restrict__ partscan,
                                             int* __restrict__ offs)
{
    int i = blockIdx.x * 256 + threadIdx.x;
    int v = (i < N_NODES) ? cnt[i] : 0;
    int lane = threadIdx.x & 63, wid = threadIdx.x >> 6;
    int incl = v;
#pragma unroll
    for (int off = 1; off < 64; off <<= 1) {
        int u = __shfl_up(incl, off);
        if (lane >= off) incl += u;
    }
    __shared__ int wsum[4];
    if (lane == 63) wsum[wid] = incl;
    __syncthreads();
    int add = partscan[blockIdx.x];
    for (int w = 0; w < wid; w++) add += wsum[w];
    if (i < N_NODES) offs[i] = incl - v + add;
    if (i == 0) offs[N_NODES] = N_EDGES;
}

__global__ __launch_bounds__(256) void k_scatter(
    const int* __restrict__ src, const int* __restrict__ dst,
    const int* __restrict__ rnk, const int* __restrict__ offs,
    int2* __restrict__ se_csr)
{
    int e = blockIdx.x * 256 + threadIdx.x;
    if (e >= N_EDGES) return;
    int p = offs[clampn(dst[e])] + rnk[e];
    se_csr[p] = make_int2(clampn(src[e]), e);
}

// ---------- K2T: wave-per-node T-factorized NNConv, p-parallel epilogue ----------
// T[d,f,i] = sum_{e->d} ea[e,f]*x[s_e,i]; h = relu(W.T + b.xs + x@root + bias)
__global__ __launch_bounds__(256) void k2T_wave(
    const float* __restrict__ x,
    const int2* __restrict__ se_csr, const int* __restrict__ offs,
    const float* __restrict__ ea,
    const float* __restrict__ mlp_w, const float* __restrict__ mlp_b,
    const float* __restrict__ ecc_root, const float* __restrict__ ecc_bias,
    const float* __restrict__ wsrc, const float* __restrict__ wdst,
    float* __restrict__ h_tab, float* __restrict__ asrc, float* __restrict__ adst)
{
    __shared__ float smW[64 * 17];   // [jj][o] pitch-17 (bank-friendly)
    __shared__ float smb[128];
    __shared__ float sroot[128];
    __shared__ float sbias[16];
    __shared__ float sws[64], swd[64];
    __shared__ float sT[4][64];
    __shared__ float sxs[4][8];

    int t = threadIdx.x;
    for (int idx = t; idx < 1024; idx += 256)
        smW[(idx >> 4) * 17 + (idx & 15)] = mlp_w[idx];
    if (t < 128) smb[t] = mlp_b[t];
    if (t >= 128 && t < 256) sroot[t - 128] = ecc_root[t - 128];
    if (t < 16) sbias[t] = ecc_bias[t];
    if (t >= 32 && t < 96) sws[t - 32] = wsrc[t - 32];
    if (t >= 96 && t < 160) swd[t - 96] = wdst[t - 96];

    int wid = t >> 6, lane = t & 63;
    int n = blockIdx.x * 4 + wid;   // grid = 12500 exactly
    int f = lane >> 3, i = lane & 7;
    int beg = offs[n], end = offs[n + 1];

    float t0 = 0.f, t1 = 0.f, t2 = 0.f, t3 = 0.f, xs = 0.f;
    int j = beg;
    for (; j + 3 < end; j += 4) {
        int2 se0 = se_csr[j],     se1 = se_csr[j + 1];
        int2 se2 = se_csr[j + 2], se3 = se_csr[j + 3];
        float a0 = ea[(size_t)se0.y * EDGE_F + f];
        float a1 = ea[(size_t)se1.y * EDGE_F + f];
        float a2 = ea[(size_t)se2.y * EDGE_F + f];
        float a3 = ea[(size_t)se3.y * EDGE_F + f];
        float x0 = x[se0.x * IN_C + i];
        float x1 = x[se1.x * IN_C + i];
        float x2 = x[se2.x * IN_C + i];
        float x3 = x[se3.x * IN_C + i];
        t0 += a0 * x0; t1 += a1 * x1; t2 += a2 * x2; t3 += a3 * x3;
        xs += (x0 + x1) + (x2 + x3);
    }
    for (; j < end; j++) {
        int2 se = se_csr[j];
        float a = ea[(size_t)se.y * EDGE_F + f];
        float xv = x[se.x * IN_C + i];
        t0 += a * xv;
        xs += xv;
    }
    sT[wid][lane] = (t0 + t1) + (t2 + t3);
    if (f == 0) sxs[wid][i] = xs;
    __syncthreads();     // covers LDS preloads + sT/sxs

    // p-parallel 64x16 contraction: lane = p*16 + o, partial over jj=p*16..+15
    int o = lane & 15, p = lane >> 4;
    float v = 0.f;
#pragma unroll
    for (int q2 = 0; q2 < 16; q2++) {
        int jj = p * 16 + q2;
        v += smW[jj * 17 + o] * sT[wid][jj];
    }
    v += __shfl_down(v, 32);
    v += __shfl_down(v, 16);    // lanes<16 hold full sums

    float hv = 0.f;
    if (lane < 16) {
        float vv = v + sbias[o];
#pragma unroll
        for (int ii = 0; ii < IN_C; ii++) {
            vv += smb[ii * 16 + o] * sxs[wid][ii];
            vv += x[n * IN_C + ii] * sroot[ii * 16 + o];
        }
        hv = fmaxf(vv, 0.f);
        h_tab[n * OUT_C + o] = hv;
    }
    // folded attention logits
    float as = 0.f, ad = 0.f;
    int h2 = lane & 3;
#pragma unroll
    for (int c = 0; c < 16; c++) {
        float hc = __shfl(hv, c);
        as += hc * sws[c * 4 + h2];
        ad += hc * swd[c * 4 + h2];
    }
    if (lane < 4) {
        asrc[n * HEADS + lane] = as;
        adst[n * HEADS + lane] = ad;
    }
}

// ---------- K_gatE: wave-per-node U accumulation, normalized in-register ----------
// lane = h*16+c; den is identical across the 16 lanes of a head -> no reduce.
__global__ __launch_bounds__(256) void k_gatE(
    const int* __restrict__ offs, const int2* __restrict__ se_csr,
    const float* __restrict__ asrc, const float* __restrict__ adst,
    const float* __restrict__ h_tab, float* __restrict__ U_all)
{
    int t = threadIdx.x;
    int wid = t >> 6, lane = t & 63;
    int n = blockIdx.x * 4 + wid;   // grid = 12500 exactly
    int h = lane >> 4, c = lane & 15;
    float adsth = adst[n * HEADS + h];
    int beg = offs[n], end = offs[n + 1];

    float U = 0.f, den = 0.f;
    int j = beg;
    for (; j + 3 < end; j += 4) {
        int s0 = se_csr[j].x,     s1 = se_csr[j + 1].x;
        int s2 = se_csr[j + 2].x, s3 = se_csr[j + 3].x;
        float av0 = asrc[s0 * HEADS + h], av1 = asrc[s1 * HEADS + h];
        float av2 = asrc[s2 * HEADS + h], av3 = asrc[s3 * HEADS + h];
        float h0 = h_tab[s0 * OUT_C + c], h1 = h_tab[s1 * OUT_C + c];
        float h2v = h_tab[s2 * OUT_C + c], h3v = h_tab[s3 * OUT_C + c];
        float v0 = av0 + adsth; v0 = v0 > 0.f ? v0 : NEG_SLOPE * v0;
        float v1 = av1 + adsth; v1 = v1 > 0.f ? v1 : NEG_SLOPE * v1;
        float v2 = av2 + adsth; v2 = v2 > 0.f ? v2 : NEG_SLOPE * v2;
        float v3 = av3 + adsth; v3 = v3 > 0.f ? v3 : NEG_SLOPE * v3;
        float p0 = __expf(v0), p1 = __expf(v1), p2 = __expf(v2), p3 = __expf(v3);
        den += (p0 + p1) + (p2 + p3);
        U += p0 * h0 + p1 * h1 + p2 * h2v + p3 * h3v;
    }
    for (; j < end; j++) {
        int s = se_csr[j].x;
        float av = asrc[s * HEADS + h];
        float hvv = h_tab[s * OUT_C + c];
        float v = av + adsth; v = v > 0.f ? v : NEG_SLOPE * v;
        float pe = __expf(v);
        den += pe;
        U += pe * hvv;
    }
    U_all[(size_t)n * 64 + lane] = U / (den + 1e-16f);
}

// ---------- K_fuse: y = relu( (Unorm @ blockdiag(gat_lin)) + gat_bias ) @ fc_w + fc_b ----------
#define BM 64
#define BK6 16
__global__ __launch_bounds__(256) void k_fuse(
    const float* __restrict__ U_all, const float* __restrict__ gat_lin,
    const float* __restrict__ gat_bias, const float* __restrict__ fc_w,
    const float* __restrict__ fc_b, float* __restrict__ y)
{
    __shared__ float sU[64 * 68];      // 17.4 KB, pitch 68
    __shared__ float slin[16 * GDIM];  // 16 KB
    __shared__ float sA[BK6][BM + 4];
    __shared__ float sW[BK6][FINAL];
    int tid = threadIdx.x;
    int r0 = blockIdx.x * BM;

    for (int idx = tid; idx < 16 * GDIM; idx += 256) slin[idx] = gat_lin[idx];
    {
        int row = tid >> 2, hq = tid & 3;
        int grow = r0 + row;
        float4 ua = make_float4(0.f, 0.f, 0.f, 0.f), ub = ua, uc = ua, ud = ua;
        if (grow < N_NODES) {
            const float* up = &U_all[(size_t)grow * 64 + hq * 16];
            ua = *(const float4*)&up[0];
            ub = *(const float4*)&up[4];
            uc = *(const float4*)&up[8];
            ud = *(const float4*)&up[12];
        }
        float* dp = &sU[row * 68 + hq * 16];
        *(float4*)&dp[0]  = ua;
        *(float4*)&dp[4]  = ub;
        *(float4*)&dp[8]  = uc;
        *(float4*)&dp[12] = ud;
    }
    __syncthreads();

    float acc[8][4];
#pragma unroll
    for (int r = 0; r < 8; r++)
#pragma unroll
        for (int c = 0; c < 4; c++) acc[r][c] = 0.f;

    int ar = tid >> 2;
    int ak = (tid & 3) * 4;
    int tcol = (tid & 31) * 4;
    int trow = (tid >> 5) * 8;

    for (int k0 = 0; k0 < GDIM; k0 += BK6) {
        int h = k0 >> 6;
        // A tile: G = Unorm @ lin, + bias, relu
        float4 bv = *(const float4*)&gat_bias[k0 + ak];
        float g0 = 0.f, g1 = 0.f, g2 = 0.f, g3 = 0.f;
        const float* urow = &sU[ar * 68 + h * 16];
#pragma unroll
        for (int c = 0; c < 16; c++) {
            float ucv = urow[c];
            const float* lp = &slin[c * GDIM + k0 + ak];
            g0 += ucv * lp[0];
            g1 += ucv * lp[1];
            g2 += ucv * lp[2];
            g3 += ucv * lp[3];
        }
        sA[ak + 0][ar] = fmaxf(g0 + bv.x, 0.f);
        sA[ak + 1][ar] = fmaxf(g1 + bv.y, 0.f);
        sA[ak + 2][ar] = fmaxf(g2 + bv.z, 0.f);
        sA[ak + 3][ar] = fmaxf(g3 + bv.w, 0.f);
#pragma unroll
        for (int p = 0; p < 2; p++) {
            int kk = (tid >> 5) + p * 8;
            int c = (tid & 31) * 4;
            *(float4*)&sW[kk][c] = *(const float4*)&fc_w[(size_t)(k0 + kk) * FINAL + c];
        }
        __syncthreads();
#pragma unroll
        for (int kk = 0; kk < BK6; kk++) {
            float4 w = *(const float4*)&sW[kk][tcol];
            float4 a0 = *(const float4*)&sA[kk][trow];
            float4 a1 = *(const float4*)&sA[kk][trow + 4];
            float a[8] = {a0.x, a0.y, a0.z, a0.w, a1.x, a1.y, a1.z, a1.w};
#pragma unroll
            for (int r = 0; r < 8; r++) {
                acc[r][0] += a[r] * w.x;
                acc[r][1] += a[r] * w.y;
                acc[r][2] += a[r] * w.z;
                acc[r][3] += a[r] * w.w;
            }
        }
        __syncthreads();
    }

    float4 fb = *(const float4*)&fc_b[tcol];
#pragma unroll
    for (int r = 0; r < 8; r++) {
        int row = r0 + trow + r;
        if (row < N_NODES) {
            *(float4*)&y[(size_t)row * FINAL + tcol] =
                make_float4(acc[r][0] + fb.x, acc[r][1] + fb.y,
                            acc[r][2] + fb.z, acc[r][3] + fb.w);
        }
    }
}

extern "C" void kernel_launch(void* const* d_in, const int* in_sizes, int n_in,
                              void* d_out, int out_size, void* d_ws, size_t ws_size,
                              hipStream_t stream)
{
    const float* x        = (const float*)d_in[0];
    const int*   ei       = (const int*)d_in[1];
    const float* ea       = (const float*)d_in[2];
    const float* ecc_root = (const float*)d_in[3];
    const float* ecc_bias = (const float*)d_in[4];
    const float* mlp_w    = (const float*)d_in[5];
    const float* mlp_b    = (const float*)d_in[6];
    const float* gat_lin  = (const float*)d_in[7];
    const float* att_src  = (const float*)d_in[8];
    const float* att_dst  = (const float*)d_in[9];
    const float* gat_bias = (const float*)d_in[10];
    const float* fc_w     = (const float*)d_in[11];
    const float* fc_b     = (const float*)d_in[12];
    float* y = (float*)d_out;

    const int* src = ei;
    const int* dst = ei + N_EDGES;

    // workspace layout
    float* h_tab = (float*)d_ws;                                  // N*16  (3.2 MB)
    float* U_all = h_tab + (size_t)N_NODES * OUT_C;               // N*64  (12.8 MB)
    float* asrc  = U_all + (size_t)N_NODES * 64;                  // N*4
    float* adst  = asrc + (size_t)N_NODES * HEADS;                // N*4
    float* wsrc  = adst + (size_t)N_NODES * HEADS;                // 64
    float* wdst  = wsrc + 64;                                     // 64
    int*   cnt      = (int*)(wdst + 64);                          // N
    int*   offs     = cnt + N_NODES;                              // N+1
    int*   part     = offs + N_NODES + 1;                         // 256
    int*   partscan = part + 256;                                 // 256
    int*   rnk      = partscan + 256;                             // E
    int2*  se_csr   = (int2*)(rnk + N_EDGES + 1);                 // E int2 (8B-aligned)

    hipMemsetAsync(cnt, 0, sizeof(int) * N_NODES, stream);

    k_histfold<<<EB + 1, 256, 0, stream>>>(dst, cnt, rnk, gat_lin, att_src, att_dst,
                                           wsrc, wdst);
    k_part    <<<NBLK, 256, 0, stream>>>(cnt, part);
    k_scan1   <<<1, 256, 0, stream>>>(part, partscan);
    k_add     <<<NBLK, 256, 0, stream>>>(cnt, partscan, offs);
    k_scatter <<<EB, 256, 0, stream>>>(src, dst, rnk, offs, se_csr);

    k2T_wave  <<<N_NODES / 4, 256, 0, stream>>>(x, se_csr, offs, ea, mlp_w, mlp_b,
                                                ecc_root, ecc_bias, wsrc, wdst,
                                                h_tab, asrc, adst);
    k_gatE    <<<N_NODES / 4, 256, 0, stream>>>(offs, se_csr, asrc, adst, h_tab, U_all);
    k_fuse    <<<(N_NODES + BM - 1) / BM, 256, 0, stream>>>(U_all, gat_lin, gat_bias,
                                                            fc_w, fc_b, y);
}